// Round 11
// baseline (343.792 us; speedup 1.0000x reference)
//
#include <hip/hip_runtime.h>
#include <math.h>

#define BB 32
#define TT 48
#define NN 360
#define HH 100
#define DD 64
#define NC 2
#define G4 400

typedef float vf4 __attribute__((ext_vector_type(4)));

__device__ __forceinline__ float sigmoid_fast(float x) {
    return 1.f / (1.f + __expf(-x));
}
__device__ __forceinline__ float tanh_fast(float x) {
    float ax = fabsf(x);
    float e = __expf(-2.f * ax);
    float t = (1.f - e) / (1.f + e);
    return copysignf(t, x);
}
__device__ __forceinline__ float dot4(float4 a, float4 b) {
    return a.x*b.x + a.y*b.y + a.z*b.z + a.w*b.w;
}
__device__ __forceinline__ float dot4v(vf4 a, float4 b) {
    return a.x*b.x + a.y*b.y + a.z*b.z + a.w*b.w;
}
__device__ __forceinline__ float bcast_lane(float v, int l) {
    return __int_as_float(__builtin_amdgcn_readlane(__float_as_int(v), l));
}
__device__ __forceinline__ vf4 ntload4(const float* p) {
    return __builtin_nontemporal_load((const vf4*)p);
}

// Wave64 sum via DPP (VALU only): row_shr 1/2/4/8 then row_bcast 15/31.
// Result valid in lane 63.
#define DPP_ADD(x, ctrl, rmask) \
    x += __int_as_float(__builtin_amdgcn_update_dpp(0, __float_as_int(x), ctrl, rmask, 0xf, true));
#define WAVE_RED(p) \
    DPP_ADD(p, 0x111, 0xf) DPP_ADD(p, 0x112, 0xf) DPP_ADD(p, 0x114, 0xf) DPP_ADD(p, 0x118, 0xf) \
    DPP_ADD(p, 0x142, 0xa) DPP_ADD(p, 0x143, 0xc)

// ---------------- K1: GCN (R9 exact — known correct) ----------------
__global__ __launch_bounds__(256) void gcn_kernel(const float* __restrict__ x,
                                                  const float* __restrict__ w,
                                                  const float* __restrict__ bptr,
                                                  float* __restrict__ gout, int nquads) {
    int tid = threadIdx.x;
    int lane = tid & 63;
    int wv = tid >> 6;                       // 0..3
    float4 wa = ((const float4*)w)[lane];
    float4 wb = (lane < 26) ? ((const float4*)w)[lane + 64] : make_float4(0.f, 0.f, 0.f, 0.f);
    float b = bptr[0];
    int stride = 4 * gridDim.x;
    for (int q = blockIdx.x * 4 + wv; q < nquads; q += stride) {
        int row0 = 4 * q;
        const float* x0 = x + (size_t)(row0 + 0) * NN;
        const float* x1 = x + (size_t)(row0 + 1) * NN;
        const float* x2 = x + (size_t)(row0 + 2) * NN;
        const float* x3 = x + (size_t)(row0 + 3) * NN;
        vf4 a0 = ntload4(x0 + 4*lane);
        vf4 a1 = ntload4(x1 + 4*lane);
        vf4 a2 = ntload4(x2 + 4*lane);
        vf4 a3 = ntload4(x3 + 4*lane);
        float p0 = dot4v(a0, wa);
        float p1 = dot4v(a1, wa);
        float p2 = dot4v(a2, wa);
        float p3 = dot4v(a3, wa);
        if (lane < 26) {                     // 90 = 64 + 26
            vf4 b0 = ntload4(x0 + 4*(lane + 64));
            vf4 b1 = ntload4(x1 + 4*(lane + 64));
            vf4 b2 = ntload4(x2 + 4*(lane + 64));
            vf4 b3 = ntload4(x3 + 4*(lane + 64));
            p0 += dot4v(b0, wb);
            p1 += dot4v(b1, wb);
            p2 += dot4v(b2, wb);
            p3 += dot4v(b3, wb);
        }
        WAVE_RED(p0)
        WAVE_RED(p1)
        WAVE_RED(p2)
        WAVE_RED(p3)
        if (lane == 63) {
            float4 r;
            r.x = fmaxf(p0 + b, 0.f);
            r.y = fmaxf(p1 + b, 0.f);
            r.z = fmaxf(p2 + b, 0.f);
            r.w = fmaxf(p3 + b, 0.f);
            ((float4*)gout)[q] = r;
        }
    }
}

// ---------------- PROBE: aligned-load + LDS-staged GCN (output unused) ----------------
// Timed only: writes to a scratch buffer no downstream kernel reads. Measures
// whether fully-aligned full-wave loads + software pipelining beat the R9 form.
#define RG 8
#define NGROUPS (BB*TT*NN/RG)        // 69120
#define GF4 (RG*NN/4)                // 720
__global__ __launch_bounds__(256) void gcn_probe_kernel(const float* __restrict__ x,
                                                        const float* __restrict__ w,
                                                        const float* __restrict__ bptr,
                                                        float* __restrict__ pout) {
    __shared__ __align__(16) float4 sbuf[4][GF4];   // 46080 B
    int tid = threadIdx.x;
    int lane = tid & 63;
    int wv = tid >> 6;
    float4* buf = sbuf[wv];
    float4 wa = ((const float4*)w)[lane];
    float4 wb = (lane < 26) ? ((const float4*)w)[lane + 64] : make_float4(0.f, 0.f, 0.f, 0.f);
    float b = bptr[0];
    int g = (blockIdx.x * 256 + tid) >> 6;
    const int gstride = (gridDim.x * 256) >> 6;
    vf4 st0, st1, st2, st3, st4, st5, st6, st7, st8, st9, st10, st11;
    if (g < NGROUPS) {
        const float* gb = x + (size_t)g * (RG * NN);
        st0  = ntload4(gb + 0*256  + 4*lane);
        st1  = ntload4(gb + 1*256  + 4*lane);
        st2  = ntload4(gb + 2*256  + 4*lane);
        st3  = ntload4(gb + 3*256  + 4*lane);
        st4  = ntload4(gb + 4*256  + 4*lane);
        st5  = ntload4(gb + 5*256  + 4*lane);
        st6  = ntload4(gb + 6*256  + 4*lane);
        st7  = ntload4(gb + 7*256  + 4*lane);
        st8  = ntload4(gb + 8*256  + 4*lane);
        st9  = ntload4(gb + 9*256  + 4*lane);
        st10 = ntload4(gb + 10*256 + 4*lane);
        if (lane < 16) st11 = ntload4(gb + 11*256 + 4*lane);
    }
    for (; g < NGROUPS; g += gstride) {
        buf[0*64  + lane] = make_float4(st0.x,  st0.y,  st0.z,  st0.w);
        buf[1*64  + lane] = make_float4(st1.x,  st1.y,  st1.z,  st1.w);
        buf[2*64  + lane] = make_float4(st2.x,  st2.y,  st2.z,  st2.w);
        buf[3*64  + lane] = make_float4(st3.x,  st3.y,  st3.z,  st3.w);
        buf[4*64  + lane] = make_float4(st4.x,  st4.y,  st4.z,  st4.w);
        buf[5*64  + lane] = make_float4(st5.x,  st5.y,  st5.z,  st5.w);
        buf[6*64  + lane] = make_float4(st6.x,  st6.y,  st6.z,  st6.w);
        buf[7*64  + lane] = make_float4(st7.x,  st7.y,  st7.z,  st7.w);
        buf[8*64  + lane] = make_float4(st8.x,  st8.y,  st8.z,  st8.w);
        buf[9*64  + lane] = make_float4(st9.x,  st9.y,  st9.z,  st9.w);
        buf[10*64 + lane] = make_float4(st10.x, st10.y, st10.z, st10.w);
        if (lane < 16) buf[11*64 + lane] = make_float4(st11.x, st11.y, st11.z, st11.w);
        int gn = g + gstride;
        if (gn < NGROUPS) {
            const float* gb = x + (size_t)gn * (RG * NN);
            st0  = ntload4(gb + 0*256  + 4*lane);
            st1  = ntload4(gb + 1*256  + 4*lane);
            st2  = ntload4(gb + 2*256  + 4*lane);
            st3  = ntload4(gb + 3*256  + 4*lane);
            st4  = ntload4(gb + 4*256  + 4*lane);
            st5  = ntload4(gb + 5*256  + 4*lane);
            st6  = ntload4(gb + 6*256  + 4*lane);
            st7  = ntload4(gb + 7*256  + 4*lane);
            st8  = ntload4(gb + 8*256  + 4*lane);
            st9  = ntload4(gb + 9*256  + 4*lane);
            st10 = ntload4(gb + 10*256 + 4*lane);
            if (lane < 16) st11 = ntload4(gb + 11*256 + 4*lane);
        }
        float s[RG];
        #pragma unroll
        for (int r = 0; r < RG; ++r) {
            float4 a = buf[r*90 + lane];
            float p = dot4(a, wa);
            if (lane < 26) p += dot4(buf[r*90 + 64 + lane], wb);
            WAVE_RED(p)
            s[r] = p;
        }
        if (lane == 63) {
            float4 o0, o1;
            o0.x = fmaxf(s[0] + b, 0.f);
            o0.y = fmaxf(s[1] + b, 0.f);
            o0.z = fmaxf(s[2] + b, 0.f);
            o0.w = fmaxf(s[3] + b, 0.f);
            o1.x = fmaxf(s[4] + b, 0.f);
            o1.y = fmaxf(s[5] + b, 0.f);
            o1.z = fmaxf(s[6] + b, 0.f);
            o1.w = fmaxf(s[7] + b, 0.f);
            ((float4*)pout)[2*g]     = o0;
            ((float4*)pout)[2*g + 1] = o1;
        }
    }
}

// ---------------- K2a: transpose W_ih [400,360] -> pair-interleaved Wt2 ----------------
__global__ void transpose_wih(const float* __restrict__ Wih, float* __restrict__ Wt2) {
    int idx = blockIdx.x * blockDim.x + threadIdx.x;
    if (idx < NN * G4) {
        int j = idx / NN, n = idx % NN;
        Wt2[n * G4 + 2 * (j % 200) + (j / 200)] = Wih[idx];
    }
}

// ---------------- K2: xproj, no LDS ----------------
__global__ __launch_bounds__(256) void xproj_kernel(const float* __restrict__ gout,
                                                    const float* __restrict__ Wt2,
                                                    const float* __restrict__ b_ih,
                                                    const float* __restrict__ b_hh,
                                                    float* __restrict__ xproj) {
    int tid = threadIdx.x;
    if (tid >= 200) return;
    int r0 = blockIdx.x * 4;
    float acc00 = 0.f, acc01 = 0.f, acc10 = 0.f, acc11 = 0.f;
    float acc20 = 0.f, acc21 = 0.f, acc30 = 0.f, acc31 = 0.f;
    const float* g0p = gout + (size_t)(r0 + 0) * NN;
    const float* g1p = gout + (size_t)(r0 + 1) * NN;
    const float* g2p = gout + (size_t)(r0 + 2) * NN;
    const float* g3p = gout + (size_t)(r0 + 3) * NN;
    const float* wp = Wt2 + 2 * tid;
    for (int n = 0; n < NN; n += 4) {
        float4 g0 = *(const float4*)(g0p + n);
        float4 g1 = *(const float4*)(g1p + n);
        float4 g2 = *(const float4*)(g2p + n);
        float4 g3 = *(const float4*)(g3p + n);
        float2 wA = *(const float2*)(wp + (n + 0) * G4);
        float2 wB = *(const float2*)(wp + (n + 1) * G4);
        float2 wC = *(const float2*)(wp + (n + 2) * G4);
        float2 wD = *(const float2*)(wp + (n + 3) * G4);
        acc00 += g0.x*wA.x + g0.y*wB.x + g0.z*wC.x + g0.w*wD.x;
        acc01 += g0.x*wA.y + g0.y*wB.y + g0.z*wC.y + g0.w*wD.y;
        acc10 += g1.x*wA.x + g1.y*wB.x + g1.z*wC.x + g1.w*wD.x;
        acc11 += g1.x*wA.y + g1.y*wB.y + g1.z*wC.y + g1.w*wD.y;
        acc20 += g2.x*wA.x + g2.y*wB.x + g2.z*wC.x + g2.w*wD.x;
        acc21 += g2.x*wA.y + g2.y*wB.y + g2.z*wC.y + g2.w*wD.y;
        acc30 += g3.x*wA.x + g3.y*wB.x + g3.z*wC.x + g3.w*wD.x;
        acc31 += g3.x*wA.y + g3.y*wB.y + g3.z*wC.y + g3.w*wD.y;
    }
    float bias0 = b_ih[tid] + b_hh[tid];
    float bias1 = b_ih[tid + 200] + b_hh[tid + 200];
    xproj[(size_t)(r0 + 0) * G4 + tid]       = acc00 + bias0;
    xproj[(size_t)(r0 + 0) * G4 + tid + 200] = acc01 + bias1;
    xproj[(size_t)(r0 + 1) * G4 + tid]       = acc10 + bias0;
    xproj[(size_t)(r0 + 1) * G4 + tid + 200] = acc11 + bias1;
    xproj[(size_t)(r0 + 2) * G4 + tid]       = acc20 + bias0;
    xproj[(size_t)(r0 + 2) * G4 + tid + 200] = acc21 + bias1;
    xproj[(size_t)(r0 + 3) * G4 + tid]       = acc30 + bias0;
    xproj[(size_t)(r0 + 3) * G4 + tid + 200] = acc31 + bias1;
}

// ---------------- K3: fused LSTM + MIL attention + classifier ----------------
__global__ __launch_bounds__(448) void lstm_attn_kernel(const float* __restrict__ xproj,
                                                        const float* __restrict__ Whh,
                                                        const float* __restrict__ wa1,
                                                        const float* __restrict__ ba1,
                                                        const float* __restrict__ wa2,
                                                        const float* __restrict__ ba2,
                                                        const float* __restrict__ wc,
                                                        const float* __restrict__ bc,
                                                        float* __restrict__ out) {
    __shared__ __align__(16) float ho[TT * HH];    // 19.2 KB
    __shared__ __align__(16) float h_lds[128];     // 100 used; 100..127 stay 0
    __shared__ float gates[G4];
    __shared__ float sc[TT];
    __shared__ float p[TT];
    __shared__ float M[HH];
    int b = blockIdx.x;
    int tid = threadIdx.x;
    int lane = tid & 63;
    float wr[HH];
    if (tid < G4) {
        #pragma unroll
        for (int k = 0; k < HH; k++) wr[k] = Whh[tid * HH + k];
    }
    float c = 0.f;
    if (tid < 128) h_lds[tid] = 0.f;
    float xp = (tid < G4) ? xproj[(size_t)(b * TT) * G4 + tid] : 0.f;
    __syncthreads();
    for (int t = 0; t < TT; t++) {
        float xp_next = (tid < G4 && t + 1 < TT)
                      ? xproj[(size_t)(b * TT + t + 1) * G4 + tid] : 0.f;
        float ha = h_lds[lane];
        float hb = h_lds[64 + lane];
        if (tid < G4) {
            float s0 = 0.f, s1 = 0.f, s2 = 0.f, s3 = 0.f;
            #pragma unroll
            for (int k = 0; k < 64; k += 4) {
                s0 += bcast_lane(ha, k+0) * wr[k+0];
                s1 += bcast_lane(ha, k+1) * wr[k+1];
                s2 += bcast_lane(ha, k+2) * wr[k+2];
                s3 += bcast_lane(ha, k+3) * wr[k+3];
            }
            #pragma unroll
            for (int k = 64; k < 100; k += 4) {
                s0 += bcast_lane(hb, k-64) * wr[k+0];
                s1 += bcast_lane(hb, k-63) * wr[k+1];
                s2 += bcast_lane(hb, k-62) * wr[k+2];
                s3 += bcast_lane(hb, k-61) * wr[k+3];
            }
            gates[tid] = xp + (s0 + s1) + (s2 + s3);
        }
        __syncthreads();
        if (tid < HH) {
            float ig = sigmoid_fast(gates[tid]);
            float fg = sigmoid_fast(gates[tid + HH]);
            float gg = tanh_fast(gates[tid + 2*HH]);
            float og = sigmoid_fast(gates[tid + 3*HH]);
            c = fg * c + ig * gg;
            float hh = og * tanh_fast(c);
            h_lds[tid] = hh;
            ho[t * HH + tid] = hh;
        }
        xp = xp_next;
        __syncthreads();
    }
    // ---- MIL attention ----
    int wave = tid >> 6;
    for (int t = wave; t < TT; t += 7) {
        float a = 0.f;
        if (lane < DD) {
            float s = ba1[lane];
            #pragma unroll
            for (int h2 = 0; h2 < HH; h2 += 4) {
                float4 h4v = *(const float4*)&ho[t*HH + h2];
                s += wa1[lane*HH + h2+0]*h4v.x + wa1[lane*HH + h2+1]*h4v.y
                   + wa1[lane*HH + h2+2]*h4v.z + wa1[lane*HH + h2+3]*h4v.w;
            }
            a = tanh_fast(s) * wa2[lane];
        }
        #pragma unroll
        for (int off = 32; off; off >>= 1) a += __shfl_down(a, off, 64);
        if (lane == 0) sc[t] = a + ba2[0];
    }
    __syncthreads();
    if (tid < 64) {
        float v = (lane < TT) ? sc[lane] : -1e30f;
        if (lane < TT) out[BB*NC + b*TT + lane] = v;      // Att (pre-softmax logits)
        float m = v;
        #pragma unroll
        for (int off = 32; off; off >>= 1) m = fmaxf(m, __shfl_xor(m, off, 64));
        float e = (lane < TT) ? __expf(v - m) : 0.f;
        float s = e;
        #pragma unroll
        for (int off = 32; off; off >>= 1) s += __shfl_xor(s, off, 64);
        if (lane < TT) p[lane] = e / s;
    }
    __syncthreads();
    if (tid < HH) {
        float m = 0.f;
        #pragma unroll
        for (int t = 0; t < TT; t++) m += p[t] * ho[t*HH + tid];
        M[tid] = m;
    }
    __syncthreads();
    if (tid == 0) {
        float l0 = bc[0], l1 = bc[1];
        for (int h2 = 0; h2 < HH; h2++) { l0 += M[h2]*wc[h2]; l1 += M[h2]*wc[HH + h2]; }
        float mx = fmaxf(l0, l1);
        float e0 = __expf(l0 - mx), e1 = __expf(l1 - mx);
        float s = e0 + e1;
        out[b*NC + 0] = e0 / s;
        out[b*NC + 1] = e1 / s;
    }
}

extern "C" void kernel_launch(void* const* d_in, const int* in_sizes, int n_in,
                              void* d_out, int out_size, void* d_ws, size_t ws_size,
                              hipStream_t stream) {
    const float* x     = (const float*)d_in[0];
    const float* w_gcn = (const float*)d_in[1];
    const float* b_gcn = (const float*)d_in[2];
    const float* W_ih  = (const float*)d_in[3];
    const float* W_hh  = (const float*)d_in[4];
    const float* b_ih  = (const float*)d_in[5];
    const float* b_hh  = (const float*)d_in[6];
    const float* wa1   = (const float*)d_in[7];
    const float* ba1   = (const float*)d_in[8];
    const float* wa2   = (const float*)d_in[9];
    const float* ba2   = (const float*)d_in[10];
    const float* wc    = (const float*)d_in[11];
    const float* bc    = (const float*)d_in[12];
    float* out = (float*)d_out;
    float* ws  = (float*)d_ws;

    float* gout  = ws;                       // 552960 floats
    float* Wt2   = gout + 552960;            // 144000 floats
    float* xproj = Wt2 + 144000;             // 614400 floats
    float* probe = xproj + 614400;           // 552960 floats (unused downstream)

    int nquads = BB * TT * NN / 4;           // 138240
    transpose_wih<<<(NN*G4 + 255)/256, 256, 0, stream>>>(W_ih, Wt2);
    gcn_kernel<<<2048, 256, 0, stream>>>(x, w_gcn, b_gcn, gout, nquads);
    xproj_kernel<<<384, 256, 0, stream>>>(gout, Wt2, b_ih, b_hh, xproj);
    lstm_attn_kernel<<<BB, 448, 0, stream>>>(xproj, W_hh, wa1, ba1, wa2, ba2, wc, bc, out);
    gcn_probe_kernel<<<768, 256, 0, stream>>>(x, w_gcn, b_gcn, probe);
}

// Round 12
// 214.205 us; speedup vs baseline: 1.6050x; 1.6050x over previous
//
#include <hip/hip_runtime.h>
#include <math.h>

#define BB 32
#define TT 48
#define NN 360
#define HH 100
#define DD 64
#define NC 2
#define G4 400

typedef float vf4 __attribute__((ext_vector_type(4)));

__device__ __forceinline__ float sigmoid_fast(float x) {
    return 1.f / (1.f + __expf(-x));
}
__device__ __forceinline__ float tanh_fast(float x) {
    float ax = fabsf(x);
    float e = __expf(-2.f * ax);
    float t = (1.f - e) / (1.f + e);
    return copysignf(t, x);
}
__device__ __forceinline__ float bcast_lane(float v, int l) {
    return __int_as_float(__builtin_amdgcn_readlane(__float_as_int(v), l));
}
__device__ __forceinline__ vf4 ntload4(const float* p) {
    return __builtin_nontemporal_load((const vf4*)p);
}
// dot of one float4 slot: mul + fma chain (explicit, mirrors R9 contraction)
__device__ __forceinline__ float dotslot(vf4 a, vf4 w) {
    return fmaf(a.w, w.w, fmaf(a.z, w.z, fmaf(a.y, w.y, a.x * w.x)));
}

// Wave64 sum via DPP (VALU only): row_shr 1/2/4/8 then row_bcast 15/31.
// Result valid in lane 63.
#define DPP_ADD(x, ctrl, rmask) \
    x += __int_as_float(__builtin_amdgcn_update_dpp(0, __float_as_int(x), ctrl, rmask, 0xf, true));
#define WAVE_RED(p) \
    DPP_ADD(p, 0x111, 0xf) DPP_ADD(p, 0x112, 0xf) DPP_ADD(p, 0x114, 0xf) DPP_ADD(p, 0x118, 0xf) \
    DPP_ADD(p, 0x142, 0xa) DPP_ADD(p, 0x143, 0xc)

// ---------------- K1: GCN — aligned staged loads, pipelined, fence-hardened ----------------
// Wave-quantum = 8 rows = 2880 floats = 11520 B (128B-aligned groups). Staged by
// 11 full-wave aligned 16B loads + one 16-lane load; reg->LDS; rows re-read from
// LDS. Next group's loads issued before processing (always in flight).
// sched_barrier(0) fences pin the write/issue/read block order against compiler
// reordering (R10 lesson); HW DS ops are in-order per wave.
#define RG 8
#define NGROUPS (BB*TT*NN/RG)        // 69120
#define GF4 (RG*NN/4)                // 720
__global__ __launch_bounds__(256) void gcn_kernel(const float* __restrict__ x,
                                                  const float* __restrict__ w,
                                                  const float* __restrict__ bptr,
                                                  float* __restrict__ gout) {
    __shared__ __align__(16) vf4 sbuf[4][GF4];   // 46080 B -> 3 blocks/CU
    int tid = threadIdx.x;
    int lane = tid & 63;
    int wv = tid >> 6;
    vf4* buf = sbuf[wv];
    vf4 wa = *(const vf4*)(w + 4*lane);
    vf4 wb;
    if (lane < 26) wb = *(const vf4*)(w + 4*(64 + lane));
    else { wb.x = 0.f; wb.y = 0.f; wb.z = 0.f; wb.w = 0.f; }
    float b = bptr[0];
    int g = blockIdx.x * 4 + wv;
    const int gstride = gridDim.x * 4;
    vf4 st0, st1, st2, st3, st4, st5, st6, st7, st8, st9, st10, st11;
    if (g < NGROUPS) {
        const float* gb = x + (size_t)g * (RG * NN);
        st0  = ntload4(gb + 0*256  + 4*lane);
        st1  = ntload4(gb + 1*256  + 4*lane);
        st2  = ntload4(gb + 2*256  + 4*lane);
        st3  = ntload4(gb + 3*256  + 4*lane);
        st4  = ntload4(gb + 4*256  + 4*lane);
        st5  = ntload4(gb + 5*256  + 4*lane);
        st6  = ntload4(gb + 6*256  + 4*lane);
        st7  = ntload4(gb + 7*256  + 4*lane);
        st8  = ntload4(gb + 8*256  + 4*lane);
        st9  = ntload4(gb + 9*256  + 4*lane);
        st10 = ntload4(gb + 10*256 + 4*lane);
        if (lane < 16) st11 = ntload4(gb + 11*256 + 4*lane);
    }
    for (; g < NGROUPS; g += gstride) {
        __builtin_amdgcn_sched_barrier(0);
        buf[0*64  + lane] = st0;
        buf[1*64  + lane] = st1;
        buf[2*64  + lane] = st2;
        buf[3*64  + lane] = st3;
        buf[4*64  + lane] = st4;
        buf[5*64  + lane] = st5;
        buf[6*64  + lane] = st6;
        buf[7*64  + lane] = st7;
        buf[8*64  + lane] = st8;
        buf[9*64  + lane] = st9;
        buf[10*64 + lane] = st10;
        if (lane < 16) buf[11*64 + lane] = st11;
        __builtin_amdgcn_sched_barrier(0);
        int gn = g + gstride;
        if (gn < NGROUPS) {
            const float* gb = x + (size_t)gn * (RG * NN);
            st0  = ntload4(gb + 0*256  + 4*lane);
            st1  = ntload4(gb + 1*256  + 4*lane);
            st2  = ntload4(gb + 2*256  + 4*lane);
            st3  = ntload4(gb + 3*256  + 4*lane);
            st4  = ntload4(gb + 4*256  + 4*lane);
            st5  = ntload4(gb + 5*256  + 4*lane);
            st6  = ntload4(gb + 6*256  + 4*lane);
            st7  = ntload4(gb + 7*256  + 4*lane);
            st8  = ntload4(gb + 8*256  + 4*lane);
            st9  = ntload4(gb + 9*256  + 4*lane);
            st10 = ntload4(gb + 10*256 + 4*lane);
            if (lane < 16) st11 = ntload4(gb + 11*256 + 4*lane);
        }
        __builtin_amdgcn_sched_barrier(0);
        float s[RG];
        #pragma unroll
        for (int r = 0; r < RG; ++r) {
            vf4 a = buf[r*90 + lane];
            float p = dotslot(a, wa);
            if (lane < 26) {
                vf4 a2 = buf[r*90 + 64 + lane];
                p += dotslot(a2, wb);        // separate dot then add (R9 order)
            }
            WAVE_RED(p)
            s[r] = p;
        }
        __builtin_amdgcn_sched_barrier(0);
        if (lane == 63) {
            float4 o0, o1;
            o0.x = fmaxf(s[0] + b, 0.f);
            o0.y = fmaxf(s[1] + b, 0.f);
            o0.z = fmaxf(s[2] + b, 0.f);
            o0.w = fmaxf(s[3] + b, 0.f);
            o1.x = fmaxf(s[4] + b, 0.f);
            o1.y = fmaxf(s[5] + b, 0.f);
            o1.z = fmaxf(s[6] + b, 0.f);
            o1.w = fmaxf(s[7] + b, 0.f);
            ((float4*)gout)[2*g]     = o0;
            ((float4*)gout)[2*g + 1] = o1;
        }
    }
}

// ---------------- K2a: transpose W_ih [400,360] -> pair-interleaved Wt2 ----------------
__global__ void transpose_wih(const float* __restrict__ Wih, float* __restrict__ Wt2) {
    int idx = blockIdx.x * blockDim.x + threadIdx.x;
    if (idx < NN * G4) {
        int j = idx / NN, n = idx % NN;
        Wt2[n * G4 + 2 * (j % 200) + (j / 200)] = Wih[idx];
    }
}

// ---------------- K2: xproj, no LDS ----------------
__global__ __launch_bounds__(256) void xproj_kernel(const float* __restrict__ gout,
                                                    const float* __restrict__ Wt2,
                                                    const float* __restrict__ b_ih,
                                                    const float* __restrict__ b_hh,
                                                    float* __restrict__ xproj) {
    int tid = threadIdx.x;
    if (tid >= 200) return;
    int r0 = blockIdx.x * 4;
    float acc00 = 0.f, acc01 = 0.f, acc10 = 0.f, acc11 = 0.f;
    float acc20 = 0.f, acc21 = 0.f, acc30 = 0.f, acc31 = 0.f;
    const float* g0p = gout + (size_t)(r0 + 0) * NN;
    const float* g1p = gout + (size_t)(r0 + 1) * NN;
    const float* g2p = gout + (size_t)(r0 + 2) * NN;
    const float* g3p = gout + (size_t)(r0 + 3) * NN;
    const float* wp = Wt2 + 2 * tid;
    for (int n = 0; n < NN; n += 4) {
        float4 g0 = *(const float4*)(g0p + n);
        float4 g1 = *(const float4*)(g1p + n);
        float4 g2 = *(const float4*)(g2p + n);
        float4 g3 = *(const float4*)(g3p + n);
        float2 wA = *(const float2*)(wp + (n + 0) * G4);
        float2 wB = *(const float2*)(wp + (n + 1) * G4);
        float2 wC = *(const float2*)(wp + (n + 2) * G4);
        float2 wD = *(const float2*)(wp + (n + 3) * G4);
        acc00 += g0.x*wA.x + g0.y*wB.x + g0.z*wC.x + g0.w*wD.x;
        acc01 += g0.x*wA.y + g0.y*wB.y + g0.z*wC.y + g0.w*wD.y;
        acc10 += g1.x*wA.x + g1.y*wB.x + g1.z*wC.x + g1.w*wD.x;
        acc11 += g1.x*wA.y + g1.y*wB.y + g1.z*wC.y + g1.w*wD.y;
        acc20 += g2.x*wA.x + g2.y*wB.x + g2.z*wC.x + g2.w*wD.x;
        acc21 += g2.x*wA.y + g2.y*wB.y + g2.z*wC.y + g2.w*wD.y;
        acc30 += g3.x*wA.x + g3.y*wB.x + g3.z*wC.x + g3.w*wD.x;
        acc31 += g3.x*wA.y + g3.y*wB.y + g3.z*wC.y + g3.w*wD.y;
    }
    float bias0 = b_ih[tid] + b_hh[tid];
    float bias1 = b_ih[tid + 200] + b_hh[tid + 200];
    xproj[(size_t)(r0 + 0) * G4 + tid]       = acc00 + bias0;
    xproj[(size_t)(r0 + 0) * G4 + tid + 200] = acc01 + bias1;
    xproj[(size_t)(r0 + 1) * G4 + tid]       = acc10 + bias0;
    xproj[(size_t)(r0 + 1) * G4 + tid + 200] = acc11 + bias1;
    xproj[(size_t)(r0 + 2) * G4 + tid]       = acc20 + bias0;
    xproj[(size_t)(r0 + 2) * G4 + tid + 200] = acc21 + bias1;
    xproj[(size_t)(r0 + 3) * G4 + tid]       = acc30 + bias0;
    xproj[(size_t)(r0 + 3) * G4 + tid + 200] = acc31 + bias1;
}

// ---------------- K3: fused LSTM + MIL attention + classifier ----------------
__global__ __launch_bounds__(448) void lstm_attn_kernel(const float* __restrict__ xproj,
                                                        const float* __restrict__ Whh,
                                                        const float* __restrict__ wa1,
                                                        const float* __restrict__ ba1,
                                                        const float* __restrict__ wa2,
                                                        const float* __restrict__ ba2,
                                                        const float* __restrict__ wc,
                                                        const float* __restrict__ bc,
                                                        float* __restrict__ out) {
    __shared__ __align__(16) float ho[TT * HH];    // 19.2 KB
    __shared__ __align__(16) float h_lds[128];     // 100 used; 100..127 stay 0
    __shared__ float gates[G4];
    __shared__ float sc[TT];
    __shared__ float p[TT];
    __shared__ float M[HH];
    int b = blockIdx.x;
    int tid = threadIdx.x;
    int lane = tid & 63;
    float wr[HH];
    if (tid < G4) {
        #pragma unroll
        for (int k = 0; k < HH; k++) wr[k] = Whh[tid * HH + k];
    }
    float c = 0.f;
    if (tid < 128) h_lds[tid] = 0.f;
    float xp = (tid < G4) ? xproj[(size_t)(b * TT) * G4 + tid] : 0.f;
    __syncthreads();
    for (int t = 0; t < TT; t++) {
        float xp_next = (tid < G4 && t + 1 < TT)
                      ? xproj[(size_t)(b * TT + t + 1) * G4 + tid] : 0.f;
        float ha = h_lds[lane];
        float hb = h_lds[64 + lane];
        if (tid < G4) {
            float s0 = 0.f, s1 = 0.f, s2 = 0.f, s3 = 0.f;
            #pragma unroll
            for (int k = 0; k < 64; k += 4) {
                s0 += bcast_lane(ha, k+0) * wr[k+0];
                s1 += bcast_lane(ha, k+1) * wr[k+1];
                s2 += bcast_lane(ha, k+2) * wr[k+2];
                s3 += bcast_lane(ha, k+3) * wr[k+3];
            }
            #pragma unroll
            for (int k = 64; k < 100; k += 4) {
                s0 += bcast_lane(hb, k-64) * wr[k+0];
                s1 += bcast_lane(hb, k-63) * wr[k+1];
                s2 += bcast_lane(hb, k-62) * wr[k+2];
                s3 += bcast_lane(hb, k-61) * wr[k+3];
            }
            gates[tid] = xp + (s0 + s1) + (s2 + s3);
        }
        __syncthreads();
        if (tid < HH) {
            float ig = sigmoid_fast(gates[tid]);
            float fg = sigmoid_fast(gates[tid + HH]);
            float gg = tanh_fast(gates[tid + 2*HH]);
            float og = sigmoid_fast(gates[tid + 3*HH]);
            c = fg * c + ig * gg;
            float hh = og * tanh_fast(c);
            h_lds[tid] = hh;
            ho[t * HH + tid] = hh;
        }
        xp = xp_next;
        __syncthreads();
    }
    // ---- MIL attention ----
    int wave = tid >> 6;
    for (int t = wave; t < TT; t += 7) {
        float a = 0.f;
        if (lane < DD) {
            float s = ba1[lane];
            #pragma unroll
            for (int h2 = 0; h2 < HH; h2 += 4) {
                float4 h4v = *(const float4*)&ho[t*HH + h2];
                s += wa1[lane*HH + h2+0]*h4v.x + wa1[lane*HH + h2+1]*h4v.y
                   + wa1[lane*HH + h2+2]*h4v.z + wa1[lane*HH + h2+3]*h4v.w;
            }
            a = tanh_fast(s) * wa2[lane];
        }
        #pragma unroll
        for (int off = 32; off; off >>= 1) a += __shfl_down(a, off, 64);
        if (lane == 0) sc[t] = a + ba2[0];
    }
    __syncthreads();
    if (tid < 64) {
        float v = (lane < TT) ? sc[lane] : -1e30f;
        if (lane < TT) out[BB*NC + b*TT + lane] = v;      // Att (pre-softmax logits)
        float m = v;
        #pragma unroll
        for (int off = 32; off; off >>= 1) m = fmaxf(m, __shfl_xor(m, off, 64));
        float e = (lane < TT) ? __expf(v - m) : 0.f;
        float s = e;
        #pragma unroll
        for (int off = 32; off; off >>= 1) s += __shfl_xor(s, off, 64);
        if (lane < TT) p[lane] = e / s;
    }
    __syncthreads();
    if (tid < HH) {
        float m = 0.f;
        #pragma unroll
        for (int t = 0; t < TT; t++) m += p[t] * ho[t*HH + tid];
        M[tid] = m;
    }
    __syncthreads();
    if (tid == 0) {
        float l0 = bc[0], l1 = bc[1];
        for (int h2 = 0; h2 < HH; h2++) { l0 += M[h2]*wc[h2]; l1 += M[h2]*wc[HH + h2]; }
        float mx = fmaxf(l0, l1);
        float e0 = __expf(l0 - mx), e1 = __expf(l1 - mx);
        float s = e0 + e1;
        out[b*NC + 0] = e0 / s;
        out[b*NC + 1] = e1 / s;
    }
}

extern "C" void kernel_launch(void* const* d_in, const int* in_sizes, int n_in,
                              void* d_out, int out_size, void* d_ws, size_t ws_size,
                              hipStream_t stream) {
    const float* x     = (const float*)d_in[0];
    const float* w_gcn = (const float*)d_in[1];
    const float* b_gcn = (const float*)d_in[2];
    const float* W_ih  = (const float*)d_in[3];
    const float* W_hh  = (const float*)d_in[4];
    const float* b_ih  = (const float*)d_in[5];
    const float* b_hh  = (const float*)d_in[6];
    const float* wa1   = (const float*)d_in[7];
    const float* ba1   = (const float*)d_in[8];
    const float* wa2   = (const float*)d_in[9];
    const float* ba2   = (const float*)d_in[10];
    const float* wc    = (const float*)d_in[11];
    const float* bc    = (const float*)d_in[12];
    float* out = (float*)d_out;
    float* ws  = (float*)d_ws;

    float* gout  = ws;                       // 552960 floats
    float* Wt2   = gout + 552960;            // 144000 floats
    float* xproj = Wt2 + 144000;             // 614400 floats

    transpose_wih<<<(NN*G4 + 255)/256, 256, 0, stream>>>(W_ih, Wt2);
    gcn_kernel<<<768, 256, 0, stream>>>(x, w_gcn, b_gcn, gout);
    xproj_kernel<<<384, 256, 0, stream>>>(gout, Wt2, b_ih, b_hh, xproj);
    lstm_attn_kernel<<<BB, 448, 0, stream>>>(xproj, W_hh, wa1, ba1, wa2, ba2, wc, bc, out);
}

// Round 14
// 213.879 us; speedup vs baseline: 1.6074x; 1.0015x over previous
//
#include <hip/hip_runtime.h>
#include <math.h>

#define BB 32
#define TT 48
#define NN 360
#define HH 100
#define DD 64
#define NC 2
#define G4 400

typedef float vf4 __attribute__((ext_vector_type(4)));

__device__ __forceinline__ float sigmoid_fast(float x) {
    return 1.f / (1.f + __expf(-x));
}
__device__ __forceinline__ float tanh_fast(float x) {
    float ax = fabsf(x);
    float e = __expf(-2.f * ax);
    float t = (1.f - e) / (1.f + e);
    return copysignf(t, x);
}
__device__ __forceinline__ float bcast_lane(float v, int l) {
    return __int_as_float(__builtin_amdgcn_readlane(__float_as_int(v), l));
}
__device__ __forceinline__ vf4 ntload4(const float* p) {
    return __builtin_nontemporal_load((const vf4*)p);
}
// dot of one float4 slot: mul + fma chain (explicit, matches R12 contraction)
__device__ __forceinline__ float dotslot(vf4 a, vf4 w) {
    return fmaf(a.w, w.w, fmaf(a.z, w.z, fmaf(a.y, w.y, a.x * w.x)));
}

// Wave64 sum via DPP (VALU only): row_shr 1/2/4/8 then row_bcast 15/31.
// Result valid in lane 63.
#define DPP_ADD(x, ctrl, rmask) \
    x += __int_as_float(__builtin_amdgcn_update_dpp(0, __float_as_int(x), ctrl, rmask, 0xf, true));
#define WAVE_RED(p) \
    DPP_ADD(p, 0x111, 0xf) DPP_ADD(p, 0x112, 0xf) DPP_ADD(p, 0x114, 0xf) DPP_ADD(p, 0x118, 0xf) \
    DPP_ADD(p, 0x142, 0xa) DPP_ADD(p, 0x143, 0xc)

// ---------------- K1: GCN — aligned staged loads, pipelined, ONE fence ----------------
// Only fence A retained (top of loop: orders previous iteration's LDS reads
// before this iteration's LDS overwrites — the only real reuse hazard, and it
// coincides with the mandatory vmcnt stall). Fences B/C/D removed so the
// compiler can hoist next-group load ISSUES above the vmcnt-stalling LDS
// writes (the probe's depth-2 schedule).
#define RG 8
#define NGROUPS (BB*TT*NN/RG)        // 69120
#define GF4 (RG*NN/4)                // 720
__global__ __launch_bounds__(256) void gcn_kernel(const float* __restrict__ x,
                                                  const float* __restrict__ w,
                                                  const float* __restrict__ bptr,
                                                  float* __restrict__ gout) {
    __shared__ __align__(16) vf4 sbuf[4][GF4];   // 46080 B -> 3 blocks/CU
    int tid = threadIdx.x;
    int lane = tid & 63;
    int wv = tid >> 6;
    vf4* buf = sbuf[wv];
    vf4 wa = *(const vf4*)(w + 4*lane);
    vf4 wb;
    if (lane < 26) wb = *(const vf4*)(w + 4*(64 + lane));
    else { wb.x = 0.f; wb.y = 0.f; wb.z = 0.f; wb.w = 0.f; }
    float b = bptr[0];
    int g = blockIdx.x * 4 + wv;
    const int gstride = gridDim.x * 4;
    vf4 st0, st1, st2, st3, st4, st5, st6, st7, st8, st9, st10, st11;
    if (g < NGROUPS) {
        const float* gb = x + (size_t)g * (RG * NN);
        st0  = ntload4(gb + 0*256  + 4*lane);
        st1  = ntload4(gb + 1*256  + 4*lane);
        st2  = ntload4(gb + 2*256  + 4*lane);
        st3  = ntload4(gb + 3*256  + 4*lane);
        st4  = ntload4(gb + 4*256  + 4*lane);
        st5  = ntload4(gb + 5*256  + 4*lane);
        st6  = ntload4(gb + 6*256  + 4*lane);
        st7  = ntload4(gb + 7*256  + 4*lane);
        st8  = ntload4(gb + 8*256  + 4*lane);
        st9  = ntload4(gb + 9*256  + 4*lane);
        st10 = ntload4(gb + 10*256 + 4*lane);
        if (lane < 16) st11 = ntload4(gb + 11*256 + 4*lane);
    }
    for (; g < NGROUPS; g += gstride) {
        __builtin_amdgcn_sched_barrier(0);   // fence A: prev reads before overwrite
        buf[0*64  + lane] = st0;
        buf[1*64  + lane] = st1;
        buf[2*64  + lane] = st2;
        buf[3*64  + lane] = st3;
        buf[4*64  + lane] = st4;
        buf[5*64  + lane] = st5;
        buf[6*64  + lane] = st6;
        buf[7*64  + lane] = st7;
        buf[8*64  + lane] = st8;
        buf[9*64  + lane] = st9;
        buf[10*64 + lane] = st10;
        if (lane < 16) buf[11*64 + lane] = st11;
        int gn = g + gstride;
        if (gn < NGROUPS) {
            const float* gb = x + (size_t)gn * (RG * NN);
            st0  = ntload4(gb + 0*256  + 4*lane);
            st1  = ntload4(gb + 1*256  + 4*lane);
            st2  = ntload4(gb + 2*256  + 4*lane);
            st3  = ntload4(gb + 3*256  + 4*lane);
            st4  = ntload4(gb + 4*256  + 4*lane);
            st5  = ntload4(gb + 5*256  + 4*lane);
            st6  = ntload4(gb + 6*256  + 4*lane);
            st7  = ntload4(gb + 7*256  + 4*lane);
            st8  = ntload4(gb + 8*256  + 4*lane);
            st9  = ntload4(gb + 9*256  + 4*lane);
            st10 = ntload4(gb + 10*256 + 4*lane);
            if (lane < 16) st11 = ntload4(gb + 11*256 + 4*lane);
        }
        float s[RG];
        #pragma unroll
        for (int r = 0; r < RG; ++r) {
            vf4 a = buf[r*90 + lane];
            float p = dotslot(a, wa);
            if (lane < 26) {
                vf4 a2 = buf[r*90 + 64 + lane];
                p += dotslot(a2, wb);
            }
            WAVE_RED(p)
            s[r] = p;
        }
        if (lane == 63) {
            float4 o0, o1;
            o0.x = fmaxf(s[0] + b, 0.f);
            o0.y = fmaxf(s[1] + b, 0.f);
            o0.z = fmaxf(s[2] + b, 0.f);
            o0.w = fmaxf(s[3] + b, 0.f);
            o1.x = fmaxf(s[4] + b, 0.f);
            o1.y = fmaxf(s[5] + b, 0.f);
            o1.z = fmaxf(s[6] + b, 0.f);
            o1.w = fmaxf(s[7] + b, 0.f);
            ((float4*)gout)[2*g]     = o0;
            ((float4*)gout)[2*g + 1] = o1;
        }
    }
}

// ---------------- K2a: transpose W_ih [400,360] -> pair-interleaved Wt2 ----------------
__global__ void transpose_wih(const float* __restrict__ Wih, float* __restrict__ Wt2) {
    int idx = blockIdx.x * blockDim.x + threadIdx.x;
    if (idx < NN * G4) {
        int j = idx / NN, n = idx % NN;
        Wt2[n * G4 + 2 * (j % 200) + (j / 200)] = Wih[idx];
    }
}

// ---------------- K2: xproj, no LDS ----------------
__global__ __launch_bounds__(256) void xproj_kernel(const float* __restrict__ gout,
                                                    const float* __restrict__ Wt2,
                                                    const float* __restrict__ b_ih,
                                                    const float* __restrict__ b_hh,
                                                    float* __restrict__ xproj) {
    int tid = threadIdx.x;
    if (tid >= 200) return;
    int r0 = blockIdx.x * 4;
    float acc00 = 0.f, acc01 = 0.f, acc10 = 0.f, acc11 = 0.f;
    float acc20 = 0.f, acc21 = 0.f, acc30 = 0.f, acc31 = 0.f;
    const float* g0p = gout + (size_t)(r0 + 0) * NN;
    const float* g1p = gout + (size_t)(r0 + 1) * NN;
    const float* g2p = gout + (size_t)(r0 + 2) * NN;
    const float* g3p = gout + (size_t)(r0 + 3) * NN;
    const float* wp = Wt2 + 2 * tid;
    for (int n = 0; n < NN; n += 4) {
        float4 g0 = *(const float4*)(g0p + n);
        float4 g1 = *(const float4*)(g1p + n);
        float4 g2 = *(const float4*)(g2p + n);
        float4 g3 = *(const float4*)(g3p + n);
        float2 wA = *(const float2*)(wp + (n + 0) * G4);
        float2 wB = *(const float2*)(wp + (n + 1) * G4);
        float2 wC = *(const float2*)(wp + (n + 2) * G4);
        float2 wD = *(const float2*)(wp + (n + 3) * G4);
        acc00 += g0.x*wA.x + g0.y*wB.x + g0.z*wC.x + g0.w*wD.x;
        acc01 += g0.x*wA.y + g0.y*wB.y + g0.z*wC.y + g0.w*wD.y;
        acc10 += g1.x*wA.x + g1.y*wB.x + g1.z*wC.x + g1.w*wD.x;
        acc11 += g1.x*wA.y + g1.y*wB.y + g1.z*wC.y + g1.w*wD.y;
        acc20 += g2.x*wA.x + g2.y*wB.x + g2.z*wC.x + g2.w*wD.x;
        acc21 += g2.x*wA.y + g2.y*wB.y + g2.z*wC.y + g2.w*wD.y;
        acc30 += g3.x*wA.x + g3.y*wB.x + g3.z*wC.x + g3.w*wD.x;
        acc31 += g3.x*wA.y + g3.y*wB.y + g3.z*wC.y + g3.w*wD.y;
    }
    float bias0 = b_ih[tid] + b_hh[tid];
    float bias1 = b_ih[tid + 200] + b_hh[tid + 200];
    xproj[(size_t)(r0 + 0) * G4 + tid]       = acc00 + bias0;
    xproj[(size_t)(r0 + 0) * G4 + tid + 200] = acc01 + bias1;
    xproj[(size_t)(r0 + 1) * G4 + tid]       = acc10 + bias0;
    xproj[(size_t)(r0 + 1) * G4 + tid + 200] = acc11 + bias1;
    xproj[(size_t)(r0 + 2) * G4 + tid]       = acc20 + bias0;
    xproj[(size_t)(r0 + 2) * G4 + tid + 200] = acc21 + bias1;
    xproj[(size_t)(r0 + 3) * G4 + tid]       = acc30 + bias0;
    xproj[(size_t)(r0 + 3) * G4 + tid + 200] = acc31 + bias1;
}

// ---------------- K3: fused LSTM + MIL attention + classifier ----------------
__global__ __launch_bounds__(448) void lstm_attn_kernel(const float* __restrict__ xproj,
                                                        const float* __restrict__ Whh,
                                                        const float* __restrict__ wa1,
                                                        const float* __restrict__ ba1,
                                                        const float* __restrict__ wa2,
                                                        const float* __restrict__ ba2,
                                                        const float* __restrict__ wc,
                                                        const float* __restrict__ bc,
                                                        float* __restrict__ out) {
    __shared__ __align__(16) float ho[TT * HH];    // 19.2 KB
    __shared__ __align__(16) float h_lds[128];     // 100 used; 100..127 stay 0
    __shared__ float gates[G4];
    __shared__ float sc[TT];
    __shared__ float p[TT];
    __shared__ float M[HH];
    int b = blockIdx.x;
    int tid = threadIdx.x;
    int lane = tid & 63;
    float wr[HH];
    if (tid < G4) {
        #pragma unroll
        for (int k = 0; k < HH; k++) wr[k] = Whh[tid * HH + k];
    }
    float c = 0.f;
    if (tid < 128) h_lds[tid] = 0.f;
    float xp = (tid < G4) ? xproj[(size_t)(b * TT) * G4 + tid] : 0.f;
    __syncthreads();
    for (int t = 0; t < TT; t++) {
        float xp_next = (tid < G4 && t + 1 < TT)
                      ? xproj[(size_t)(b * TT + t + 1) * G4 + tid] : 0.f;
        float ha = h_lds[lane];
        float hb = h_lds[64 + lane];
        if (tid < G4) {
            float s0 = 0.f, s1 = 0.f, s2 = 0.f, s3 = 0.f;
            #pragma unroll
            for (int k = 0; k < 64; k += 4) {
                s0 += bcast_lane(ha, k+0) * wr[k+0];
                s1 += bcast_lane(ha, k+1) * wr[k+1];
                s2 += bcast_lane(ha, k+2) * wr[k+2];
                s3 += bcast_lane(ha, k+3) * wr[k+3];
            }
            #pragma unroll
            for (int k = 64; k < 100; k += 4) {
                s0 += bcast_lane(hb, k-64) * wr[k+0];
                s1 += bcast_lane(hb, k-63) * wr[k+1];
                s2 += bcast_lane(hb, k-62) * wr[k+2];
                s3 += bcast_lane(hb, k-61) * wr[k+3];
            }
            gates[tid] = xp + (s0 + s1) + (s2 + s3);
        }
        __syncthreads();
        if (tid < HH) {
            float ig = sigmoid_fast(gates[tid]);
            float fg = sigmoid_fast(gates[tid + HH]);
            float gg = tanh_fast(gates[tid + 2*HH]);
            float og = sigmoid_fast(gates[tid + 3*HH]);
            c = fg * c + ig * gg;
            float hh = og * tanh_fast(c);
            h_lds[tid] = hh;
            ho[t * HH + tid] = hh;
        }
        xp = xp_next;
        __syncthreads();
    }
    // ---- MIL attention ----
    int wave = tid >> 6;
    for (int t = wave; t < TT; t += 7) {
        float a = 0.f;
        if (lane < DD) {
            float s = ba1[lane];
            #pragma unroll
            for (int h2 = 0; h2 < HH; h2 += 4) {
                float4 h4v = *(const float4*)&ho[t*HH + h2];
                s += wa1[lane*HH + h2+0]*h4v.x + wa1[lane*HH + h2+1]*h4v.y
                   + wa1[lane*HH + h2+2]*h4v.z + wa1[lane*HH + h2+3]*h4v.w;
            }
            a = tanh_fast(s) * wa2[lane];
        }
        #pragma unroll
        for (int off = 32; off; off >>= 1) a += __shfl_down(a, off, 64);
        if (lane == 0) sc[t] = a + ba2[0];
    }
    __syncthreads();
    if (tid < 64) {
        float v = (lane < TT) ? sc[lane] : -1e30f;
        if (lane < TT) out[BB*NC + b*TT + lane] = v;      // Att (pre-softmax logits)
        float m = v;
        #pragma unroll
        for (int off = 32; off; off >>= 1) m = fmaxf(m, __shfl_xor(m, off, 64));
        float e = (lane < TT) ? __expf(v - m) : 0.f;
        float s = e;
        #pragma unroll
        for (int off = 32; off; off >>= 1) s += __shfl_xor(s, off, 64);
        if (lane < TT) p[lane] = e / s;
    }
    __syncthreads();
    if (tid < HH) {
        float m = 0.f;
        #pragma unroll
        for (int t = 0; t < TT; t++) m += p[t] * ho[t*HH + tid];
        M[tid] = m;
    }
    __syncthreads();
    if (tid == 0) {
        float l0 = bc[0], l1 = bc[1];
        for (int h2 = 0; h2 < HH; h2++) { l0 += M[h2]*wc[h2]; l1 += M[h2]*wc[HH + h2]; }
        float mx = fmaxf(l0, l1);
        float e0 = __expf(l0 - mx), e1 = __expf(l1 - mx);
        float s = e0 + e1;
        out[b*NC + 0] = e0 / s;
        out[b*NC + 1] = e1 / s;
    }
}

extern "C" void kernel_launch(void* const* d_in, const int* in_sizes, int n_in,
                              void* d_out, int out_size, void* d_ws, size_t ws_size,
                              hipStream_t stream) {
    const float* x     = (const float*)d_in[0];
    const float* w_gcn = (const float*)d_in[1];
    const float* b_gcn = (const float*)d_in[2];
    const float* W_ih  = (const float*)d_in[3];
    const float* W_hh  = (const float*)d_in[4];
    const float* b_ih  = (const float*)d_in[5];
    const float* b_hh  = (const float*)d_in[6];
    const float* wa1   = (const float*)d_in[7];
    const float* ba1   = (const float*)d_in[8];
    const float* wa2   = (const float*)d_in[9];
    const float* ba2   = (const float*)d_in[10];
    const float* wc    = (const float*)d_in[11];
    const float* bc    = (const float*)d_in[12];
    float* out = (float*)d_out;
    float* ws  = (float*)d_ws;

    float* gout  = ws;                       // 552960 floats
    float* Wt2   = gout + 552960;            // 144000 floats
    float* xproj = Wt2 + 144000;             // 614400 floats

    transpose_wih<<<(NN*G4 + 255)/256, 256, 0, stream>>>(W_ih, Wt2);
    gcn_kernel<<<768, 256, 0, stream>>>(x, w_gcn, b_gcn, gout);
    xproj_kernel<<<384, 256, 0, stream>>>(gout, Wt2, b_ih, b_hh, xproj);
    lstm_attn_kernel<<<BB, 448, 0, stream>>>(xproj, W_hh, wa1, ba1, wa2, ba2, wc, bc, out);
}

// Round 15
// 213.809 us; speedup vs baseline: 1.6079x; 1.0003x over previous
//
#include <hip/hip_runtime.h>
#include <math.h>

#define BB 32
#define TT 48
#define NN 360
#define HH 100
#define DD 64
#define NC 2
#define G4 400

typedef float vf4 __attribute__((ext_vector_type(4)));

__device__ __forceinline__ float sigmoid_fast(float x) {
    return 1.f / (1.f + __expf(-x));
}
__device__ __forceinline__ float tanh_fast(float x) {
    float ax = fabsf(x);
    float e = __expf(-2.f * ax);
    float t = (1.f - e) / (1.f + e);
    return copysignf(t, x);
}
__device__ __forceinline__ float bcast_lane(float v, int l) {
    return __int_as_float(__builtin_amdgcn_readlane(__float_as_int(v), l));
}
__device__ __forceinline__ vf4 ntload4(const float* p) {
    return __builtin_nontemporal_load((const vf4*)p);
}
// dot of one float4 slot: mul + fma chain (matches R14 contraction, absmax 1.5e-5)
__device__ __forceinline__ float dotslot(vf4 a, vf4 w) {
    return fmaf(a.w, w.w, fmaf(a.z, w.z, fmaf(a.y, w.y, a.x * w.x)));
}

// Wave64 sum via DPP (VALU only): row_shr 1/2/4/8 then row_bcast 15/31.
// Result valid in lane 63.
#define DPP_ADD(x, ctrl, rmask) \
    x += __int_as_float(__builtin_amdgcn_update_dpp(0, __float_as_int(x), ctrl, rmask, 0xf, true));
#define WAVE_RED(p) \
    DPP_ADD(p, 0x111, 0xf) DPP_ADD(p, 0x112, 0xf) DPP_ADD(p, 0x114, 0xf) DPP_ADD(p, 0x118, 0xf) \
    DPP_ADD(p, 0x142, 0xa) DPP_ADD(p, 0x143, 0xc)

// ---------------- K1: GCN — aligned staged loads, MANUAL 2-deep pipeline ----------------
// R14 lost the probe's win because st0..st11 are reused every iteration: the
// LDS-write of group i (vmcnt-waits on i's loads) WAR-blocks issuing group
// i+1's loads, and fence A stops the compiler renaming across the back-edge.
// Fix: two explicit register sets (sa/sb, ping-pong). The set being written
// to LDS finished loading TWO iterations ago (vmcnt satisfied); the other
// set's loads stay in flight under this iteration's compute. Fence A kept
// (LDS overwrite vs prior reads aliasing; R10 lesson). Math identical to R14.
#define RG 8
#define NGROUPS (BB*TT*NN/RG)        // 69120
#define GF4 (RG*NN/4)                // 720
#define LOADG(S, gidx) do { if ((gidx) < NGROUPS) { \
    const float* gb_ = x + (size_t)(gidx) * (RG * NN); \
    S##0  = ntload4(gb_ + 0*256  + 4*lane); \
    S##1  = ntload4(gb_ + 1*256  + 4*lane); \
    S##2  = ntload4(gb_ + 2*256  + 4*lane); \
    S##3  = ntload4(gb_ + 3*256  + 4*lane); \
    S##4  = ntload4(gb_ + 4*256  + 4*lane); \
    S##5  = ntload4(gb_ + 5*256  + 4*lane); \
    S##6  = ntload4(gb_ + 6*256  + 4*lane); \
    S##7  = ntload4(gb_ + 7*256  + 4*lane); \
    S##8  = ntload4(gb_ + 8*256  + 4*lane); \
    S##9  = ntload4(gb_ + 9*256  + 4*lane); \
    S##10 = ntload4(gb_ + 10*256 + 4*lane); \
    if (lane < 16) S##11 = ntload4(gb_ + 11*256 + 4*lane); \
} } while (0)
#define WRITELDS(S) do { \
    buf[0*64  + lane] = S##0; \
    buf[1*64  + lane] = S##1; \
    buf[2*64  + lane] = S##2; \
    buf[3*64  + lane] = S##3; \
    buf[4*64  + lane] = S##4; \
    buf[5*64  + lane] = S##5; \
    buf[6*64  + lane] = S##6; \
    buf[7*64  + lane] = S##7; \
    buf[8*64  + lane] = S##8; \
    buf[9*64  + lane] = S##9; \
    buf[10*64 + lane] = S##10; \
    if (lane < 16) buf[11*64 + lane] = S##11; \
} while (0)
#define COMPUTE_STORE(gcur) do { \
    float s_[RG]; \
    _Pragma("unroll") \
    for (int r = 0; r < RG; ++r) { \
        vf4 a_ = buf[r*90 + lane]; \
        float p_ = dotslot(a_, wa); \
        if (lane < 26) { vf4 a2_ = buf[r*90 + 64 + lane]; p_ += dotslot(a2_, wb); } \
        WAVE_RED(p_) \
        s_[r] = p_; \
    } \
    if (lane == 63) { \
        float4 o0_, o1_; \
        o0_.x = fmaxf(s_[0] + b, 0.f); o0_.y = fmaxf(s_[1] + b, 0.f); \
        o0_.z = fmaxf(s_[2] + b, 0.f); o0_.w = fmaxf(s_[3] + b, 0.f); \
        o1_.x = fmaxf(s_[4] + b, 0.f); o1_.y = fmaxf(s_[5] + b, 0.f); \
        o1_.z = fmaxf(s_[6] + b, 0.f); o1_.w = fmaxf(s_[7] + b, 0.f); \
        ((float4*)gout)[2*(gcur)]     = o0_; \
        ((float4*)gout)[2*(gcur) + 1] = o1_; \
    } \
} while (0)

__global__ __launch_bounds__(256) void gcn_kernel(const float* __restrict__ x,
                                                  const float* __restrict__ w,
                                                  const float* __restrict__ bptr,
                                                  float* __restrict__ gout) {
    __shared__ __align__(16) vf4 sbuf[4][GF4];   // 46080 B -> 3 blocks/CU
    int tid = threadIdx.x;
    int lane = tid & 63;
    int wv = tid >> 6;
    vf4* buf = sbuf[wv];
    vf4 wa = *(const vf4*)(w + 4*lane);
    vf4 wb;
    if (lane < 26) wb = *(const vf4*)(w + 4*(64 + lane));
    else { wb.x = 0.f; wb.y = 0.f; wb.z = 0.f; wb.w = 0.f; }
    float b = bptr[0];
    const int gstride = gridDim.x * 4;
    int g = blockIdx.x * 4 + wv;
    vf4 sa0, sa1, sa2, sa3, sa4, sa5, sa6, sa7, sa8, sa9, sa10, sa11;
    vf4 sb0, sb1, sb2, sb3, sb4, sb5, sb6, sb7, sb8, sb9, sb10, sb11;
    LOADG(sa, g);
    LOADG(sb, g + gstride);
    for (int g2 = g; g2 < NGROUPS; ) {
        __builtin_amdgcn_sched_barrier(0);   // fence A: prev LDS reads before overwrite
        WRITELDS(sa);                        // sa's loads finished 2 iters ago
        LOADG(sa, g2 + 2*gstride);           // refill sa; in flight 2 iters
        COMPUTE_STORE(g2);
        g2 += gstride;
        if (g2 >= NGROUPS) break;
        __builtin_amdgcn_sched_barrier(0);
        WRITELDS(sb);
        LOADG(sb, g2 + 2*gstride);
        COMPUTE_STORE(g2);
        g2 += gstride;
    }
}

// ---------------- K2a: transpose W_ih [400,360] -> pair-interleaved Wt2 ----------------
__global__ void transpose_wih(const float* __restrict__ Wih, float* __restrict__ Wt2) {
    int idx = blockIdx.x * blockDim.x + threadIdx.x;
    if (idx < NN * G4) {
        int j = idx / NN, n = idx % NN;
        Wt2[n * G4 + 2 * (j % 200) + (j / 200)] = Wih[idx];
    }
}

// ---------------- K2: xproj, no LDS ----------------
__global__ __launch_bounds__(256) void xproj_kernel(const float* __restrict__ gout,
                                                    const float* __restrict__ Wt2,
                                                    const float* __restrict__ b_ih,
                                                    const float* __restrict__ b_hh,
                                                    float* __restrict__ xproj) {
    int tid = threadIdx.x;
    if (tid >= 200) return;
    int r0 = blockIdx.x * 4;
    float acc00 = 0.f, acc01 = 0.f, acc10 = 0.f, acc11 = 0.f;
    float acc20 = 0.f, acc21 = 0.f, acc30 = 0.f, acc31 = 0.f;
    const float* g0p = gout + (size_t)(r0 + 0) * NN;
    const float* g1p = gout + (size_t)(r0 + 1) * NN;
    const float* g2p = gout + (size_t)(r0 + 2) * NN;
    const float* g3p = gout + (size_t)(r0 + 3) * NN;
    const float* wp = Wt2 + 2 * tid;
    for (int n = 0; n < NN; n += 4) {
        float4 g0 = *(const float4*)(g0p + n);
        float4 g1 = *(const float4*)(g1p + n);
        float4 g2 = *(const float4*)(g2p + n);
        float4 g3 = *(const float4*)(g3p + n);
        float2 wA = *(const float2*)(wp + (n + 0) * G4);
        float2 wB = *(const float2*)(wp + (n + 1) * G4);
        float2 wC = *(const float2*)(wp + (n + 2) * G4);
        float2 wD = *(const float2*)(wp + (n + 3) * G4);
        acc00 += g0.x*wA.x + g0.y*wB.x + g0.z*wC.x + g0.w*wD.x;
        acc01 += g0.x*wA.y + g0.y*wB.y + g0.z*wC.y + g0.w*wD.y;
        acc10 += g1.x*wA.x + g1.y*wB.x + g1.z*wC.x + g1.w*wD.x;
        acc11 += g1.x*wA.y + g1.y*wB.y + g1.z*wC.y + g1.w*wD.y;
        acc20 += g2.x*wA.x + g2.y*wB.x + g2.z*wC.x + g2.w*wD.x;
        acc21 += g2.x*wA.y + g2.y*wB.y + g2.z*wC.y + g2.w*wD.y;
        acc30 += g3.x*wA.x + g3.y*wB.x + g3.z*wC.x + g3.w*wD.x;
        acc31 += g3.x*wA.y + g3.y*wB.y + g3.z*wC.y + g3.w*wD.y;
    }
    float bias0 = b_ih[tid] + b_hh[tid];
    float bias1 = b_ih[tid + 200] + b_hh[tid + 200];
    xproj[(size_t)(r0 + 0) * G4 + tid]       = acc00 + bias0;
    xproj[(size_t)(r0 + 0) * G4 + tid + 200] = acc01 + bias1;
    xproj[(size_t)(r0 + 1) * G4 + tid]       = acc10 + bias0;
    xproj[(size_t)(r0 + 1) * G4 + tid + 200] = acc11 + bias1;
    xproj[(size_t)(r0 + 2) * G4 + tid]       = acc20 + bias0;
    xproj[(size_t)(r0 + 2) * G4 + tid + 200] = acc21 + bias1;
    xproj[(size_t)(r0 + 3) * G4 + tid]       = acc30 + bias0;
    xproj[(size_t)(r0 + 3) * G4 + tid + 200] = acc31 + bias1;
}

// ---------------- K3: fused LSTM + MIL attention + classifier ----------------
__global__ __launch_bounds__(448) void lstm_attn_kernel(const float* __restrict__ xproj,
                                                        const float* __restrict__ Whh,
                                                        const float* __restrict__ wa1,
                                                        const float* __restrict__ ba1,
                                                        const float* __restrict__ wa2,
                                                        const float* __restrict__ ba2,
                                                        const float* __restrict__ wc,
                                                        const float* __restrict__ bc,
                                                        float* __restrict__ out) {
    __shared__ __align__(16) float ho[TT * HH];    // 19.2 KB
    __shared__ __align__(16) float h_lds[128];     // 100 used; 100..127 stay 0
    __shared__ float gates[G4];
    __shared__ float sc[TT];
    __shared__ float p[TT];
    __shared__ float M[HH];
    int b = blockIdx.x;
    int tid = threadIdx.x;
    int lane = tid & 63;
    float wr[HH];
    if (tid < G4) {
        #pragma unroll
        for (int k = 0; k < HH; k++) wr[k] = Whh[tid * HH + k];
    }
    float c = 0.f;
    if (tid < 128) h_lds[tid] = 0.f;
    float xp = (tid < G4) ? xproj[(size_t)(b * TT) * G4 + tid] : 0.f;
    __syncthreads();
    for (int t = 0; t < TT; t++) {
        float xp_next = (tid < G4 && t + 1 < TT)
                      ? xproj[(size_t)(b * TT + t + 1) * G4 + tid] : 0.f;
        float ha = h_lds[lane];
        float hb = h_lds[64 + lane];
        if (tid < G4) {
            float s0 = 0.f, s1 = 0.f, s2 = 0.f, s3 = 0.f;
            #pragma unroll
            for (int k = 0; k < 64; k += 4) {
                s0 += bcast_lane(ha, k+0) * wr[k+0];
                s1 += bcast_lane(ha, k+1) * wr[k+1];
                s2 += bcast_lane(ha, k+2) * wr[k+2];
                s3 += bcast_lane(ha, k+3) * wr[k+3];
            }
            #pragma unroll
            for (int k = 64; k < 100; k += 4) {
                s0 += bcast_lane(hb, k-64) * wr[k+0];
                s1 += bcast_lane(hb, k-63) * wr[k+1];
                s2 += bcast_lane(hb, k-62) * wr[k+2];
                s3 += bcast_lane(hb, k-61) * wr[k+3];
            }
            gates[tid] = xp + (s0 + s1) + (s2 + s3);
        }
        __syncthreads();
        if (tid < HH) {
            float ig = sigmoid_fast(gates[tid]);
            float fg = sigmoid_fast(gates[tid + HH]);
            float gg = tanh_fast(gates[tid + 2*HH]);
            float og = sigmoid_fast(gates[tid + 3*HH]);
            c = fg * c + ig * gg;
            float hh = og * tanh_fast(c);
            h_lds[tid] = hh;
            ho[t * HH + tid] = hh;
        }
        xp = xp_next;
        __syncthreads();
    }
    // ---- MIL attention ----
    int wave = tid >> 6;
    for (int t = wave; t < TT; t += 7) {
        float a = 0.f;
        if (lane < DD) {
            float s = ba1[lane];
            #pragma unroll
            for (int h2 = 0; h2 < HH; h2 += 4) {
                float4 h4v = *(const float4*)&ho[t*HH + h2];
                s += wa1[lane*HH + h2+0]*h4v.x + wa1[lane*HH + h2+1]*h4v.y
                   + wa1[lane*HH + h2+2]*h4v.z + wa1[lane*HH + h2+3]*h4v.w;
            }
            a = tanh_fast(s) * wa2[lane];
        }
        #pragma unroll
        for (int off = 32; off; off >>= 1) a += __shfl_down(a, off, 64);
        if (lane == 0) sc[t] = a + ba2[0];
    }
    __syncthreads();
    if (tid < 64) {
        float v = (lane < TT) ? sc[lane] : -1e30f;
        if (lane < TT) out[BB*NC + b*TT + lane] = v;      // Att (pre-softmax logits)
        float m = v;
        #pragma unroll
        for (int off = 32; off; off >>= 1) m = fmaxf(m, __shfl_xor(m, off, 64));
        float e = (lane < TT) ? __expf(v - m) : 0.f;
        float s = e;
        #pragma unroll
        for (int off = 32; off; off >>= 1) s += __shfl_xor(s, off, 64);
        if (lane < TT) p[lane] = e / s;
    }
    __syncthreads();
    if (tid < HH) {
        float m = 0.f;
        #pragma unroll
        for (int t = 0; t < TT; t++) m += p[t] * ho[t*HH + tid];
        M[tid] = m;
    }
    __syncthreads();
    if (tid == 0) {
        float l0 = bc[0], l1 = bc[1];
        for (int h2 = 0; h2 < HH; h2++) { l0 += M[h2]*wc[h2]; l1 += M[h2]*wc[HH + h2]; }
        float mx = fmaxf(l0, l1);
        float e0 = __expf(l0 - mx), e1 = __expf(l1 - mx);
        float s = e0 + e1;
        out[b*NC + 0] = e0 / s;
        out[b*NC + 1] = e1 / s;
    }
}

extern "C" void kernel_launch(void* const* d_in, const int* in_sizes, int n_in,
                              void* d_out, int out_size, void* d_ws, size_t ws_size,
                              hipStream_t stream) {
    const float* x     = (const float*)d_in[0];
    const float* w_gcn = (const float*)d_in[1];
    const float* b_gcn = (const float*)d_in[2];
    const float* W_ih  = (const float*)d_in[3];
    const float* W_hh  = (const float*)d_in[4];
    const float* b_ih  = (const float*)d_in[5];
    const float* b_hh  = (const float*)d_in[6];
    const float* wa1   = (const float*)d_in[7];
    const float* ba1   = (const float*)d_in[8];
    const float* wa2   = (const float*)d_in[9];
    const float* ba2   = (const float*)d_in[10];
    const float* wc    = (const float*)d_in[11];
    const float* bc    = (const float*)d_in[12];
    float* out = (float*)d_out;
    float* ws  = (float*)d_ws;

    float* gout  = ws;                       // 552960 floats
    float* Wt2   = gout + 552960;            // 144000 floats
    float* xproj = Wt2 + 144000;             // 614400 floats

    transpose_wih<<<(NN*G4 + 255)/256, 256, 0, stream>>>(W_ih, Wt2);
    gcn_kernel<<<768, 256, 0, stream>>>(x, w_gcn, b_gcn, gout);
    xproj_kernel<<<384, 256, 0, stream>>>(gout, Wt2, b_ih, b_hh, xproj);
    lstm_attn_kernel<<<BB, 448, 0, stream>>>(xproj, W_hh, wa1, ba1, wa2, ba2, wc, bc, out);
}